// Round 4
// baseline (445.594 us; speedup 1.0000x reference)
//
#include <hip/hip_runtime.h>
#include <hip/hip_bf16.h>

#define BB 32
#define SS 4096
#define HH 512
#define EE 512
#define NCH 64          // 64-row s-chunks per b
#define QSEG 8          // split-K segments for q-projection
#define NEGV -1000000000.0f

using float4v = __attribute__((ext_vector_type(4))) float;
using short8v = __attribute__((ext_vector_type(8))) short;

#if defined(__has_builtin)
#if __has_builtin(__builtin_amdgcn_sched_barrier)
#define SCHED_FENCE() __builtin_amdgcn_sched_barrier(0)
#endif
#if __has_builtin(__builtin_amdgcn_rcpf)
#define FAST_RCP(x) __builtin_amdgcn_rcpf(x)
#endif
#if __has_builtin(__builtin_amdgcn_exp2f)
#define FAST_EXP2(x) __builtin_amdgcn_exp2f(x)
#endif
#if __has_builtin(__builtin_amdgcn_s_setprio)
#define SETPRIO(n) __builtin_amdgcn_s_setprio(n)
#endif
#endif
#ifndef SCHED_FENCE
#define SCHED_FENCE()
#endif
#ifndef FAST_RCP
#define FAST_RCP(x) (1.0f / (x))
#endif
#ifndef FAST_EXP2
#define FAST_EXP2(x) __expf(0.69314718056f * (x))
#endif
#ifndef SETPRIO
#define SETPRIO(n)
#endif

__device__ inline unsigned short f2bf(float x) {
    union { float f; unsigned int u; } c; c.f = x;
    unsigned int r = c.u + 0x7FFFu + ((c.u >> 16) & 1u);  // RNE
    return (unsigned short)(r >> 16);
}
__device__ inline float bf2f(unsigned short s) {
    union { float f; unsigned int u; } c; c.u = ((unsigned int)s) << 16;
    return c.f;
}
__device__ inline unsigned int pk2bf(float a, float b) {  // packed RNE cvt
    union { __hip_bfloat162 h; unsigned int u; } c;
    c.h = __float22bfloat162_rn(float2{a, b});
    return c.u;
}

// Merged prep: blocks [0,256) compute 8-way split-K q-projection partials;
// blocks [256,384) repack Wk (E,H) fp32 -> fragment-linear bf16 via an LDS
// transpose tile so the global reads are fully coalesced (256B bursts).
__global__ void prep_kernel(const float* __restrict__ query, const float* __restrict__ Wq,
                            float* __restrict__ qp8,
                            const float* __restrict__ Wk, unsigned short* __restrict__ WkT) {
    int bx = blockIdx.x, t = threadIdx.x;  // 256 threads
    if (bx < QSEG * BB) {
        __shared__ float qs[64];
        int b = bx >> 3, seg = bx & 7;
        if (t < 64) qs[t] = query[b * HH + seg * 64 + t];
        __syncthreads();
        float a0 = 0.f, a1 = 0.f;
        const float* wq = Wq + (size_t)(seg * 64) * HH;
        #pragma unroll 8
        for (int e = 0; e < 64; ++e) {
            float q = qs[e];
            a0 += q * wq[(size_t)e * HH + t];
            a1 += q * wq[(size_t)e * HH + t + 256];
        }
        qp8[((size_t)seg * BB + b) * HH + t] = a0;
        qp8[((size_t)seg * BB + b) * HH + t + 256] = a1;
    } else {
        // tile: 32 e-rows (one ks slice) x 64 h-cols; 128 blocks total
        int tile = bx - QSEG * BB;      // 0..127
        int ks = tile >> 3;             // 0..15 -> e0 = ks*32
        int h0 = (tile & 7) * 64;       // h tile base
        __shared__ float wt[32][67];    // 67-stride: lq rows land on distinct banks
        #pragma unroll
        for (int p = 0; p < 2; ++p) {
            int idx = t + p * 256;      // 512 float4 groups: 16 per row, 32 rows
            int r = idx >> 4, c4 = idx & 15;
            float4v wv = *(const float4v*)(Wk + (size_t)(ks * 32 + r) * HH + h0 + c4 * 4);
            wt[r][c4 * 4 + 0] = wv.x; wt[r][c4 * 4 + 1] = wv.y;
            wt[r][c4 * 4 + 2] = wv.z; wt[r][c4 * 4 + 3] = wv.w;
        }
        __syncthreads();
        int lane = t & 63, ntl = t >> 6;      // 4 nt per tile, one frag per thread
        int lq = lane >> 4, lr = lane & 15;
        int nt = (h0 >> 4) + ntl;
        short8v o;
        #pragma unroll
        for (int j = 0; j < 8; ++j)
            o[j] = (short)f2bf(wt[lq * 8 + j][ntl * 16 + lr]);
        size_t g = ((size_t)ks * 32 + nt) * 64 + lane;
        *(short8v*)(WkT + g * 8) = o;
    }
}

// Fused scores + online-softmax stats + context partial. grid (NCH, B), 1024 thr.
// 16 waves, each wave: 4 m-tiles x 2 nt-tiles -> acc[4][2] = 32 AGPRs, so the
// whole kernel fits 128 unified regs -> 4 waves/SIMD resident (r3 ran at 2).
// Keys segments issued TWO ahead (>=1200cy flight >> 900cy HBM latency);
// WkT fragments prefetched TWO k-slices ahead (~300cy flight >= L2 latency).
__launch_bounds__(1024, 4)
__global__ void fused_kernel(const float* __restrict__ keys, const unsigned short* __restrict__ WkT,
                             const float* __restrict__ qp8, const float* __restrict__ bq,
                             const float* __restrict__ bk, const float* __restrict__ v,
                             const float* __restrict__ bv, const int* __restrict__ mask,
                             float* __restrict__ pe_out, float* __restrict__ part,
                             float* __restrict__ marr, float* __restrict__ larr) {
    constexpr int LDK = EE + 8;                 // 520 shorts, 1040B row stride
    __shared__ unsigned short klds[64 * LDK];   // 66.5 KB
    __shared__ float qp_lds[HH];
    __shared__ float v_lds[HH];
    __shared__ float red[16][64];               // 4 KB
    __shared__ float p_lds[64];
    __shared__ float ctxred[4][EE];             // 8 KB  (total ~83 KB)
    int b = blockIdx.y, c = blockIdx.x, s0 = c * 64;
    int tid = threadIdx.x;

    // issue seg0 AND seg1 keys loads first (deep HBM flight), then small L2 reads
    const float4v* ksrc = (const float4v*)(keys + ((size_t)b * SS + s0) * EE);
    float4v kva[2], kvb[2];
    #pragma unroll
    for (int p = 0; p < 2; ++p) {
        int idx = tid + p * 1024;
        kva[p] = ksrc[(size_t)(idx >> 5) * 128 + (idx & 31)];
    }
    #pragma unroll
    for (int p = 0; p < 2; ++p) {
        int idx = tid + p * 1024;
        kvb[p] = ksrc[(size_t)(idx >> 5) * 128 + 32 + (idx & 31)];
    }
    int mval = 0;
    if (tid < 64) mval = mask[b * SS + s0 + tid];  // prefetch; used at the end

    for (int i = tid; i < HH; i += 1024) {
        float qv = 0.f;
        #pragma unroll
        for (int sg = 0; sg < QSEG; ++sg) qv += qp8[((size_t)sg * BB + b) * HH + i];
        qp_lds[i] = qv + bq[i] + bk[i];
        v_lds[i] = v[i];
    }

    // store seg0 (the only HBM-latency-exposed wait; happens once per block)
    #pragma unroll
    for (int p = 0; p < 2; ++p) {
        int idx = tid + p * 1024, row = idx >> 5, c4 = idx & 31;
        unsigned int u0 = pk2bf(kva[p].x, kva[p].y), u1 = pk2bf(kva[p].z, kva[p].w);
        *(uint2*)(&klds[row * LDK + c4 * 4]) = make_uint2(u0, u1);
    }

    int w = tid >> 6, lane = tid & 63;
    int lq = lane >> 4, lr = lane & 15;
    int nt_lo = w * 2;                          // this wave's 2 nt-tiles
    const short8v* Wf = (const short8v*)WkT;

    // WkT prefetch ring, depth 2: slices 0 and 1 in flight before the barrier
    short8v bf0[2], bf1[2], bf2[2];
    #pragma unroll
    for (int j = 0; j < 2; ++j) bf0[j] = Wf[(size_t)(nt_lo + j) * 64 + lane];
    #pragma unroll
    for (int j = 0; j < 2; ++j) bf1[j] = Wf[((size_t)32 + nt_lo + j) * 64 + lane];

    float4v acc[4][2];
    #pragma unroll
    for (int m = 0; m < 4; ++m)
        #pragma unroll
        for (int j = 0; j < 2; ++j) acc[m][j] = (float4v){0.f, 0.f, 0.f, 0.f};

    __syncthreads();

    #pragma unroll
    for (int q = 0; q < 4; ++q) {
        if (q < 2) {  // issue seg q+2 into the buffer freed by the last store
            #pragma unroll
            for (int p = 0; p < 2; ++p) {
                int idx = tid + p * 1024;
                float4v t4 = ksrc[(size_t)(idx >> 5) * 128 + (q + 2) * 32 + (idx & 31)];
                if (q == 0) kva[p] = t4; else kvb[p] = t4;
            }
        }
        SCHED_FENCE();
        #pragma unroll
        for (int ksl = 0; ksl < 4; ++ksl) {
            int kq = q * 4 + ksl;
            if (kq < 14) {  // prefetch slice kq+2 (compile-time guard)
                #pragma unroll
                for (int j = 0; j < 2; ++j)
                    bf2[j] = Wf[((size_t)(kq + 2) * 32 + nt_lo + j) * 64 + lane];
            }
            SETPRIO(1);
            #pragma unroll
            for (int m = 0; m < 4; ++m) {
                short8v afrag = *(const short8v*)(&klds[(m * 16 + lr) * LDK + kq * 32 + lq * 8]);
                #pragma unroll
                for (int j = 0; j < 2; ++j)
                    acc[m][j] = __builtin_amdgcn_mfma_f32_16x16x32_bf16(afrag, bf0[j], acc[m][j], 0, 0, 0);
            }
            SETPRIO(0);
            #pragma unroll
            for (int j = 0; j < 2; ++j) { bf0[j] = bf1[j]; bf1[j] = bf2[j]; }
        }
        if (q < 3) {  // store seg q+1 (loads have had >=8 slices of flight)
            #pragma unroll
            for (int p = 0; p < 2; ++p) {
                int idx = tid + p * 1024, row = idx >> 5, c4 = (q + 1) * 32 + (idx & 31);
                float4v t4 = (q & 1) ? kva[p] : kvb[p];
                unsigned int u0 = pk2bf(t4.x, t4.y), u1 = pk2bf(t4.z, t4.w);
                *(uint2*)(&klds[row * LDK + c4 * 4]) = make_uint2(u0, u1);
            }
            __syncthreads();
        }
    }

    // tanh epilogue: pr += v[h] - 2 v[h] / (2^(2/ln2 * x)+1)   (== v[h]*tanh(x))
    float pr[4][4];
    #pragma unroll
    for (int m = 0; m < 4; ++m)
        #pragma unroll
        for (int r = 0; r < 4; ++r) pr[m][r] = 0.f;
    #pragma unroll
    for (int j = 0; j < 2; ++j) {
        int h = (nt_lo + j) * 16 + lr;
        float vj = v_lds[h], qj = qp_lds[h], vj2 = -2.f * vj;
        #pragma unroll
        for (int m = 0; m < 4; ++m) {
            #pragma unroll
            for (int r = 0; r < 4; ++r) {
                float x = qj + acc[m][j][r];
                float rr = FAST_RCP(FAST_EXP2(2.885390082f * x) + 1.f);
                pr[m][r] += __builtin_fmaf(vj2, rr, vj);
            }
        }
    }
    #pragma unroll
    for (int m = 0; m < 4; ++m)
        #pragma unroll
        for (int r = 0; r < 4; ++r) {
            float p = pr[m][r];
            p += __shfl_xor(p, 1, 16);
            p += __shfl_xor(p, 2, 16);
            p += __shfl_xor(p, 4, 16);
            p += __shfl_xor(p, 8, 16);
            pr[m][r] = p;
        }
    if (lr == 0) {
        #pragma unroll
        for (int m = 0; m < 4; ++m)
            #pragma unroll
            for (int r = 0; r < 4; ++r)
                red[w][m * 16 + lq * 4 + r] = pr[m][r];
    }
    __syncthreads();

    // wave 0: final score, mask, chunk-local softmax stats; store pe (not raw score)
    if (tid < 64) {
        float sc = bv[0];
        #pragma unroll
        for (int ww = 0; ww < 16; ++ww) sc += red[ww][tid];
        if (mval == 0) sc = NEGV;
        float mv = sc;
        #pragma unroll
        for (int off = 1; off < 64; off <<= 1) mv = fmaxf(mv, __shfl_xor(mv, off));
        float pe = __expf(sc - mv);
        float ls = pe;
        #pragma unroll
        for (int off = 1; off < 64; off <<= 1) ls += __shfl_xor(ls, off);
        p_lds[tid] = pe;
        pe_out[b * SS + s0 + tid] = pe;
        if (tid == 0) { marr[b * NCH + c] = mv; larr[b * NCH + c] = ls; }
    }
    __syncthreads();

    // context partial from the retained LDS tile: o[e] = sum_s p[s]*keys[s][e]
    // paired-b32 reads, rows split 4 ways across thread quarters (16 iters each).
    {
        int rq = tid >> 8, c2 = (tid & 255) * 2;
        float e0 = 0.f, e1 = 0.f;
        #pragma unroll 8
        for (int s = 0; s < 16; ++s) {
            int row = rq * 16 + s;
            unsigned int u = *(const unsigned int*)(&klds[row * LDK + c2]);
            float ps = p_lds[row];
            e0 = __builtin_fmaf(ps, bf2f((unsigned short)(u & 0xffffu)), e0);
            e1 = __builtin_fmaf(ps, bf2f((unsigned short)(u >> 16)), e1);
        }
        *(float2*)(&ctxred[rq][c2]) = make_float2(e0, e1);
    }
    __syncthreads();
    if (tid < EE)
        part[((size_t)b * NCH + c) * EE + tid] =
            ctxred[0][tid] + ctxred[1][tid] + ctxred[2][tid] + ctxred[3][tid];
}

// Merge chunk partials; grid (4, B): x==0 writes ctx, all x write attn slices.
// attn[s] = pe[s] * exp(m_chunk - M) / L  (identical math, no re-exp of scores)
__global__ void finalize_kernel(const float* __restrict__ pe_arr, const float* __restrict__ part,
                                const float* __restrict__ marr, const float* __restrict__ larr,
                                float* __restrict__ ctx, float* __restrict__ attn) {
    __shared__ float wgt[NCH];
    __shared__ float Ls;
    int b = blockIdx.y, px = blockIdx.x, t = threadIdx.x;  // 512 threads
    if (t < NCH) {
        float m = marr[b * NCH + t], l = larr[b * NCH + t];
        float M = m;
        #pragma unroll
        for (int off = 1; off < 64; off <<= 1) M = fmaxf(M, __shfl_xor(M, off));
        float wq = __expf(m - M);
        float L = wq * l;
        #pragma unroll
        for (int off = 1; off < 64; off <<= 1) L += __shfl_xor(L, off);
        wgt[t] = wq;
        if (t == 0) Ls = L;
    }
    __syncthreads();
    float invL = 1.f / Ls;
    if (px == 0) {
        float o = 0.f;
        #pragma unroll 8
        for (int cc = 0; cc < NCH; ++cc)
            o += wgt[cc] * part[((size_t)b * NCH + cc) * EE + t];
        ctx[b * EE + t] = o * invL;
    }
    int s0 = px * 1024;
    attn[b * SS + s0 + t]       = pe_arr[b * SS + s0 + t]       * wgt[(s0 + t) >> 6]       * invL;
    attn[b * SS + s0 + t + 512] = pe_arr[b * SS + s0 + t + 512] * wgt[(s0 + t + 512) >> 6] * invL;
}

extern "C" void kernel_launch(void* const* d_in, const int* in_sizes, int n_in,
                              void* d_out, int out_size, void* d_ws, size_t ws_size,
                              hipStream_t stream) {
    const float* query = (const float*)d_in[0];
    const float* keys  = (const float*)d_in[1];
    const int*   mask  = (const int*)d_in[2];
    const float* Wq    = (const float*)d_in[3];
    const float* bq    = (const float*)d_in[4];
    const float* Wk    = (const float*)d_in[5];
    const float* bk    = (const float*)d_in[6];
    const float* v     = (const float*)d_in[7];
    const float* bv    = (const float*)d_in[8];

    float* out  = (float*)d_out;
    float* ctx  = out;            // (B, E)
    float* attn = out + BB * EE;  // (B, S)

    char* ws = (char*)d_ws;
    float* qp8          = (float*)ws;                         // 8*32*512*4 = 524288 B
    unsigned short* WkT = (unsigned short*)(ws + 524288);     // 524288 B
    float* pe           = (float*)(ws + 1048576);             // 524288 B
    float* part         = (float*)(ws + 1572864);             // 4194304 B
    float* marr         = (float*)(ws + 5767168);             // 8192 B
    float* larr         = (float*)(ws + 5775360);             // 8192 B

    prep_kernel<<<QSEG * BB + 128, 256, 0, stream>>>(query, Wq, qp8, Wk, WkT);
    fused_kernel<<<dim3(NCH, BB), 1024, 0, stream>>>(keys, WkT, qp8, bq, bk, v, bv, mask,
                                                     pe, part, marr, larr);
    finalize_kernel<<<dim3(4, BB), 512, 0, stream>>>(pe, part, marr, larr, ctx, attn);
}